// Round 5
// baseline (300.026 us; speedup 1.0000x reference)
//
#include <hip/hip_runtime.h>

// FeatureFlowAttention (local_window_attn=1, r=1), b=4, c=128, h=w=128.
// score(p,p') = x_p^T M x_p' + gamma_p + delta_p' + d,  M = Wq^T Wk.
// Transposed form: z_p = M^T x_p + v  ->  score_k(p) = z_p . x_{p+dk} + gamma_p + d.
// Pipeline (2 kernels, r3 structure + DPP phase C):
//   prep:  MT = (Wq^T Wk)^T split to bf16 (MhT,MlT); u, v, d.
//   fused: per image-row block (512 thr, XCD-chunked rowid): stage MT in LDS
//          (XOR-swizzled) -> MFMA split-bf16 z in registers (lane owns 1 px x
//          32 ch) -> 9-shift scores: center-column loads only, col+-1 via DPP
//          row_shr/shl within 16-lane rows (edge lanes m=0/15 do a predicated
//          3-row edge load feeding the DPP 'old' operand) -> shfl_xor channel
//          reduce -> softmax -> flow gather. One barrier total.

#define HW 16384
#define NB 4
#define TOT (NB * HW)   // 65536 pixels

typedef short bf16x8 __attribute__((ext_vector_type(8)));
typedef float f32x4 __attribute__((ext_vector_type(4)));

__device__ __forceinline__ unsigned short f2bf(float f) {   // RNE float->bf16
    unsigned u = __float_as_uint(f);
    return (unsigned short)((u + 0x7fffu + ((u >> 16) & 1u)) >> 16);
}
__device__ __forceinline__ float bf2f(unsigned short s) {
    return __uint_as_float(((unsigned)s) << 16);
}
// DPP within 16-lane rows. row_shr:1 (0x111): lane i <- lane i-1 (i%16==0 -> old).
// row_shl:1 (0x101): lane i <- lane i+1 (i%16==15 -> old). bound_ctrl=false: keep old.
__device__ __forceinline__ float dpp_shr1(float old_, float src) {
    return __int_as_float(__builtin_amdgcn_update_dpp(
        __float_as_int(old_), __float_as_int(src), 0x111, 0xf, 0xf, false));
}
__device__ __forceinline__ float dpp_shl1(float old_, float src) {
    return __int_as_float(__builtin_amdgcn_update_dpp(
        __float_as_int(old_), __float_as_int(src), 0x101, 0xf, 0xf, false));
}

// ---------------- prep ----------------------------------------------------------
// blocks 0..127: MT row ci = bid:  MT[ci][cj] = sum_co kw[co][ci]*qw[co][cj]
// block 128: u[t] = sum qw[co][t]*kb[co]; v[t] = sum kw[co][t]*qb[co]; d = qb.kb
__global__ void prep_kernel(const float* __restrict__ qw, const float* __restrict__ qb,
                            const float* __restrict__ kw, const float* __restrict__ kb,
                            unsigned short* __restrict__ MhT, unsigned short* __restrict__ MlT,
                            float* __restrict__ u, float* __restrict__ v,
                            float* __restrict__ dptr) {
    __shared__ float red[128];
    int bid = blockIdx.x, tid = threadIdx.x;
    if (bid < 128) {
        int ci = bid;
        int cj = tid & 127, half = tid >> 7;
        int co0 = half * 64;
        const float* kcol = kw + ci;
        float acc = 0.f;
#pragma unroll 4
        for (int co = 0; co < 64; ++co)
            acc += kcol[(size_t)(co0 + co) * 128] * qw[(size_t)(co0 + co) * 128 + cj];
        if (half) red[cj] = acc;
        __syncthreads();
        if (!half) {
            float mval = acc + red[cj];
            unsigned short h = f2bf(mval);
            MhT[ci * 128 + cj] = h;
            MlT[ci * 128 + cj] = f2bf(mval - bf2f(h));
        }
    } else {
        int half = tid >> 7, t = tid & 127;
        const float* w  = half ? kw : qw;
        const float* bv = half ? qb : kb;
        float acc = 0.f;
#pragma unroll 4
        for (int co = 0; co < 128; ++co) acc += w[co * 128 + t] * bv[co];
        if (half) v[t] = acc; else u[t] = acc;
        if (!half) red[t] = qb[t] * kb[t];
        __syncthreads();
        if (tid == 0) {
            float dd = 0.f;
            for (int i = 0; i < 128; ++i) dd += red[i];
            *dptr = dd;
        }
    }
}

// ---------------- fused ---------------------------------------------------------
// Grid 512 = 4 images x 128 rows, XCD-chunked: rowid = (bid&7)*64 + (bid>>3).
// Verified layouts (16x16x32 bf16): A[m=lane&15][k=(lane>>4)*8+j];
// B[k=(lane>>4)*8+j][n=lane&15]; D col=lane&15, row=(lane>>4)*4+reg.
__global__ __launch_bounds__(512, 4)
void fused_kernel(const float* __restrict__ feat,
                  const unsigned short* __restrict__ MhT, const unsigned short* __restrict__ MlT,
                  const float* __restrict__ u, const float* __restrict__ v,
                  const float* __restrict__ dptr, const float* __restrict__ flow,
                  float* __restrict__ out) {
    __shared__ char lds[65536];   // swizzled MhT (0..32767) + MlT (32768..65535)
    int tid = threadIdx.x;
    int bid = blockIdx.x;
    int rowid = (bid & 7) * 64 + (bid >> 3);
    int b = rowid >> 7, row = rowid & 127;
    int p0 = row * 128;

    // ---- Phase A: stage swizzled MT into LDS. byte swizzle: off ^= ((ci&7)<<4)
#pragma unroll
    for (int it = 0; it < 4; ++it) {
        int off = (it * 512 + tid) * 16;           // byte offset in 32 KB half
        int swz = off ^ (((off >> 8) & 7) << 4);
        *(bf16x8*)(lds + swz) = *(const bf16x8*)((const char*)MhT + off);
        *(bf16x8*)(lds + 32768 + swz) = *(const bf16x8*)((const char*)MlT + off);
    }
    __syncthreads();   // the kernel's only barrier

    int wave = tid >> 6, lane = tid & 63;
    int m = lane & 15, q = lane >> 4;
    int col = wave * 16 + m;                       // column within the row
    const float* xbase = feat + (size_t)b * 128 * HW + p0 + wave * 16;

    // ---- Phase B: z = M^T x + v (in registers)
    f32x4 zero = {0.f, 0.f, 0.f, 0.f};
    f32x4 acc[8];
#pragma unroll
    for (int t = 0; t < 8; ++t) acc[t] = zero;

#pragma unroll
    for (int kc = 0; kc < 4; ++kc) {
        int c0 = kc * 32;
        const float* xp = xbase + (size_t)(c0 + q * 8) * HW + m;
        float xv[8];
#pragma unroll
        for (int j = 0; j < 8; ++j) xv[j] = xp[(size_t)j * HW];
        bf16x8 bh, bl;
#pragma unroll
        for (int j = 0; j < 8; ++j) {
            unsigned short hh = f2bf(xv[j]);
            bh[j] = (short)hh;
            bl[j] = (short)f2bf(xv[j] - bf2f(hh));
        }
        int colb = (c0 + q * 8) * 2;
        int swzx = (m & 7) << 4;
#pragma unroll
        for (int t = 0; t < 8; ++t) {
            int offr = ((t * 16 + m) * 256 + colb) ^ swzx;
            bf16x8 ah = *(const bf16x8*)(lds + offr);
            bf16x8 al = *(const bf16x8*)(lds + 32768 + offr);
            acc[t] = __builtin_amdgcn_mfma_f32_16x16x32_bf16(ah, bh, acc[t], 0, 0, 0);
            acc[t] = __builtin_amdgcn_mfma_f32_16x16x32_bf16(ah, bl, acc[t], 0, 0, 0);
            acc[t] = __builtin_amdgcn_mfma_f32_16x16x32_bf16(al, bh, acc[t], 0, 0, 0);
        }
    }
    // z = acc + v  (delta bias folded into z; neighbor dot then includes delta_p')
#pragma unroll
    for (int t = 0; t < 8; ++t) {
        float4 vv = *(const float4*)(v + t * 16 + q * 4);
#pragma unroll
        for (int r = 0; r < 4; ++r) acc[t][r] += ((const float*)&vv)[r];
    }

    // ---- Phase C: 9-shift scores + gamma.
    // Center-column loads only; col-1/col+1 via DPP within the 16-lane row.
    // Edge lanes (m==0 needs col-1 = prev wave's last col; m==15 needs col+1)
    // do a predicated 3-row load that feeds the DPP 'old' operand.
    int a0 = (row > 0 ? row - 1 : 0) * 128;
    int a1 = row * 128;
    int a2 = (row < 127 ? row + 1 : 127) * 128;
    int cm = col > 0 ? col - 1 : 0;
    int cp = col < 127 ? col + 1 : 127;
    int ecol = (m == 15) ? cp : cm;                // used only by m==0 / m==15
    bool isedge = (m == 0) || (m == 15);
    const float* fb = feat + (size_t)b * 128 * HW;

    float sc[9];
#pragma unroll
    for (int k = 0; k < 9; ++k) sc[k] = 0.f;
    float g = 0.f;

#pragma unroll
    for (int t = 0; t < 8; ++t) {
        float4 uu = *(const float4*)(u + t * 16 + q * 4);
#pragma unroll
        for (int r = 0; r < 4; ++r) {
            float zv = acc[t][r];
            const float* xc = fb + (size_t)(t * 16 + q * 4 + r) * HW;
            float e0 = 0.f, e1 = 0.f, e2 = 0.f;
            if (isedge) {                          // 2 active lanes per 16-row
                const float* eb = xc + ecol;
                e0 = eb[a0]; e1 = eb[a1]; e2 = eb[a2];
            }
            float c0v = xc[a0 + col];
            float c1v = xc[a1 + col];
            float c2v = xc[a2 + col];
            float m0 = dpp_shr1(e0, c0v), pl0 = dpp_shl1(e0, c0v);
            float m1 = dpp_shr1(e1, c1v), pl1 = dpp_shl1(e1, c1v);
            float m2 = dpp_shr1(e2, c2v), pl2 = dpp_shl1(e2, c2v);
            sc[0] += zv * m0; sc[1] += zv * c0v; sc[2] += zv * pl0;
            sc[3] += zv * m1; sc[4] += zv * c1v; sc[5] += zv * pl1;
            sc[6] += zv * m2; sc[7] += zv * c2v; sc[8] += zv * pl2;
            g += ((const float*)&uu)[r] * c1v;
        }
    }

    // ---- channel reduce across the 4 q-groups (lane bits 4,5)
#pragma unroll
    for (int k = 0; k < 9; ++k) {
        sc[k] += __shfl_xor(sc[k], 16);
        sc[k] += __shfl_xor(sc[k], 32);
    }
    g += __shfl_xor(g, 16);
    g += __shfl_xor(g, 32);

    // ---- softmax + flow gather (all lanes compute; q==0 lanes store)
    const float inv = 0.08838834764831845f;       // 1/sqrt(128)
    float base = g + *dptr;
    bool rok0 = row > 0, rok2 = row < 127;
    bool cok0 = col > 0, cok2 = col < 127;
    bool vmask[9] = { rok0 && cok0, rok0, rok0 && cok2,
                      cok0,         true, cok2,
                      rok2 && cok0, rok2, rok2 && cok2 };

    float s[9];
    float mx = -1e30f;
#pragma unroll
    for (int k = 0; k < 9; ++k) {
        float sv = vmask[k] ? (sc[k] + base) * inv : 0.f;
        s[k] = sv;
        mx = fmaxf(mx, sv);
    }
    float e[9], sum = 0.f;
#pragma unroll
    for (int k = 0; k < 9; ++k) { e[k] = __expf(s[k] - mx); sum += e[k]; }
    float rs = 1.f / sum;

    const float* f0 = flow + (size_t)(b * 2) * HW;
    const float* f1 = f0 + HW;
    int av[3] = {a0, a1, a2};
    int cv[3] = {cm, col, cp};
    float o0 = 0.f, o1 = 0.f;
#pragma unroll
    for (int dy = 0; dy < 3; ++dy)
#pragma unroll
        for (int dx = 0; dx < 3; ++dx) {
            int k = dy * 3 + dx;
            float pr = vmask[k] ? e[k] * rs : 0.f;
            int off = av[dy] + cv[dx];
            o0 += pr * f0[off];
            o1 += pr * f1[off];
        }
    if (q == 0) {
        out[(size_t)(b * 2) * HW + p0 + col] = o0;
        out[(size_t)(b * 2 + 1) * HW + p0 + col] = o1;
    }
}

extern "C" void kernel_launch(void* const* d_in, const int* in_sizes, int n_in,
                              void* d_out, int out_size, void* d_ws, size_t ws_size,
                              hipStream_t stream) {
    const float* feat = (const float*)d_in[0];
    const float* flow = (const float*)d_in[1];
    const float* qw = (const float*)d_in[2];
    const float* qb = (const float*)d_in[3];
    const float* kw = (const float*)d_in[4];
    const float* kb = (const float*)d_in[5];

    float* ws = (float*)d_ws;
    float* u = ws;                              // 128
    float* v = ws + 128;                        // 128
    float* dptr = ws + 256;                     // 1 (pad to 512)
    unsigned short* MhT = (unsigned short*)(ws + 512);    // 16384 bf16 = 8192 fl
    unsigned short* MlT = (unsigned short*)(ws + 8704);   // 16384 bf16 = 8192 fl
    float* out = (float*)d_out;

    prep_kernel<<<129, 256, 0, stream>>>(qw, qb, kw, kb, MhT, MlT, u, v, dptr);
    fused_kernel<<<512, 512, 0, stream>>>(feat, MhT, MlT, u, v, dptr, flow, out);
}

// Round 6
// 108.207 us; speedup vs baseline: 2.7727x; 2.7727x over previous
//
#include <hip/hip_runtime.h>

// FeatureFlowAttention (local_window_attn=1, r=1), b=4, c=128, h=w=128.
// score(p,p') = x_p^T M x_p' + gamma_p + delta_p' + d,  M = Wq^T Wk.
// Transposed form: z_p = M^T x_p + v  ->  score_k(p) = z_p . x_{p+dk} + gamma_p + d.
// Pipeline (2 kernels) — PROVEN r3 structure (108.8 us):
//   prep:  MT = (Wq^T Wk)^T split to bf16 (MhT,MlT); u, v, d.
//   fused: per image-row block (512 thr, XCD-chunked rowid): stage MT in LDS
//          (XOR-swizzled) -> MFMA split-bf16 z kept IN REGISTERS (lane owns 1 px
//          x 32 ch) -> score vs x-halo with hoisted row/col clamps (clamped
//          addresses only feed masked entries) -> shfl_xor channel reduce ->
//          softmax -> flow gather. One barrier total; z never touches LDS.
// NOTE (r5 lesson): phase C sits just under the 128-VGPR cliff of
// __launch_bounds__(512,4). DPP neighbor-sharing added ~12 live temps/iter,
// collapsed the allocator to 64 VGPR + ~480 MB scratch spill traffic (3x regress).
// Do not add live state to phase C.

#define HW 16384
#define NB 4
#define TOT (NB * HW)   // 65536 pixels

typedef short bf16x8 __attribute__((ext_vector_type(8)));
typedef float f32x4 __attribute__((ext_vector_type(4)));

__device__ __forceinline__ unsigned short f2bf(float f) {   // RNE float->bf16
    unsigned u = __float_as_uint(f);
    return (unsigned short)((u + 0x7fffu + ((u >> 16) & 1u)) >> 16);
}
__device__ __forceinline__ float bf2f(unsigned short s) {
    return __uint_as_float(((unsigned)s) << 16);
}

// ---------------- prep ----------------------------------------------------------
// blocks 0..127: MT row ci = bid:  MT[ci][cj] = sum_co kw[co][ci]*qw[co][cj]
// block 128: u[t] = sum qw[co][t]*kb[co]; v[t] = sum kw[co][t]*qb[co]; d = qb.kb
__global__ void prep_kernel(const float* __restrict__ qw, const float* __restrict__ qb,
                            const float* __restrict__ kw, const float* __restrict__ kb,
                            unsigned short* __restrict__ MhT, unsigned short* __restrict__ MlT,
                            float* __restrict__ u, float* __restrict__ v,
                            float* __restrict__ dptr) {
    __shared__ float red[128];
    int bid = blockIdx.x, tid = threadIdx.x;
    if (bid < 128) {
        int ci = bid;
        int cj = tid & 127, half = tid >> 7;
        int co0 = half * 64;
        const float* kcol = kw + ci;
        float acc = 0.f;
#pragma unroll 4
        for (int co = 0; co < 64; ++co)
            acc += kcol[(size_t)(co0 + co) * 128] * qw[(size_t)(co0 + co) * 128 + cj];
        if (half) red[cj] = acc;
        __syncthreads();
        if (!half) {
            float mval = acc + red[cj];
            unsigned short h = f2bf(mval);
            MhT[ci * 128 + cj] = h;
            MlT[ci * 128 + cj] = f2bf(mval - bf2f(h));
        }
    } else {
        int half = tid >> 7, t = tid & 127;
        const float* w  = half ? kw : qw;
        const float* bv = half ? qb : kb;
        float acc = 0.f;
#pragma unroll 4
        for (int co = 0; co < 128; ++co) acc += w[co * 128 + t] * bv[co];
        if (half) v[t] = acc; else u[t] = acc;
        if (!half) red[t] = qb[t] * kb[t];
        __syncthreads();
        if (tid == 0) {
            float dd = 0.f;
            for (int i = 0; i < 128; ++i) dd += red[i];
            *dptr = dd;
        }
    }
}

// ---------------- fused ---------------------------------------------------------
// Grid 512 = 4 images x 128 rows, XCD-chunked: rowid = (bid&7)*64 + (bid>>3) so
// each XCD's 64 co-resident blocks cover a contiguous row band (halo L2-hits).
// Verified layouts (16x16x32 bf16): A[m=lane&15][k=(lane>>4)*8+j];
// B[k=(lane>>4)*8+j][n=lane&15]; D col=lane&15, row=(lane>>4)*4+reg.
// Wave w: 16 px (cols w*16..w*16+15); lane: px col=w*16+(lane&15), channel set
// c = t*16 + q*4 + r (q=lane>>4, t=0..7, r=0..3) -> 32 z values in acc regs.
__global__ __launch_bounds__(512, 4)
void fused_kernel(const float* __restrict__ feat,
                  const unsigned short* __restrict__ MhT, const unsigned short* __restrict__ MlT,
                  const float* __restrict__ u, const float* __restrict__ v,
                  const float* __restrict__ dptr, const float* __restrict__ flow,
                  float* __restrict__ out) {
    __shared__ char lds[65536];   // swizzled MhT (0..32767) + MlT (32768..65535)
    int tid = threadIdx.x;
    int bid = blockIdx.x;
    int rowid = (bid & 7) * 64 + (bid >> 3);
    int b = rowid >> 7, row = rowid & 127;
    int p0 = row * 128;

    // ---- Phase A: stage swizzled MT into LDS. byte swizzle: off ^= ((ci&7)<<4)
#pragma unroll
    for (int it = 0; it < 4; ++it) {
        int off = (it * 512 + tid) * 16;           // byte offset in 32 KB half
        int swz = off ^ (((off >> 8) & 7) << 4);
        *(bf16x8*)(lds + swz) = *(const bf16x8*)((const char*)MhT + off);
        *(bf16x8*)(lds + 32768 + swz) = *(const bf16x8*)((const char*)MlT + off);
    }
    __syncthreads();   // the kernel's only barrier

    int wave = tid >> 6, lane = tid & 63;
    int m = lane & 15, q = lane >> 4;
    int col = wave * 16 + m;                       // column within the row
    const float* xbase = feat + (size_t)b * 128 * HW + p0 + wave * 16;

    // ---- Phase B: z = M^T x + v (in registers)
    f32x4 zero = {0.f, 0.f, 0.f, 0.f};
    f32x4 acc[8];
#pragma unroll
    for (int t = 0; t < 8; ++t) acc[t] = zero;

#pragma unroll
    for (int kc = 0; kc < 4; ++kc) {
        int c0 = kc * 32;
        const float* xp = xbase + (size_t)(c0 + q * 8) * HW + m;
        float xv[8];
#pragma unroll
        for (int j = 0; j < 8; ++j) xv[j] = xp[(size_t)j * HW];
        bf16x8 bh, bl;
#pragma unroll
        for (int j = 0; j < 8; ++j) {
            unsigned short hh = f2bf(xv[j]);
            bh[j] = (short)hh;
            bl[j] = (short)f2bf(xv[j] - bf2f(hh));
        }
        int colb = (c0 + q * 8) * 2;
        int swzx = (m & 7) << 4;
#pragma unroll
        for (int t = 0; t < 8; ++t) {
            int offr = ((t * 16 + m) * 256 + colb) ^ swzx;
            bf16x8 ah = *(const bf16x8*)(lds + offr);
            bf16x8 al = *(const bf16x8*)(lds + 32768 + offr);
            acc[t] = __builtin_amdgcn_mfma_f32_16x16x32_bf16(ah, bh, acc[t], 0, 0, 0);
            acc[t] = __builtin_amdgcn_mfma_f32_16x16x32_bf16(ah, bl, acc[t], 0, 0, 0);
            acc[t] = __builtin_amdgcn_mfma_f32_16x16x32_bf16(al, bh, acc[t], 0, 0, 0);
        }
    }
    // z = acc + v  (delta bias folded into z; neighbor dot then includes delta_p')
#pragma unroll
    for (int t = 0; t < 8; ++t) {
        float4 vv = *(const float4*)(v + t * 16 + q * 4);
#pragma unroll
        for (int r = 0; r < 4; ++r) acc[t][r] += ((const float*)&vv)[r];
    }

    // ---- Phase C: 9-shift scores + gamma, hoisted clamps (clamped -> masked)
    int a0 = (row > 0 ? row - 1 : 0) * 128;
    int a1 = row * 128;
    int a2 = (row < 127 ? row + 1 : 127) * 128;
    int cm = col > 0 ? col - 1 : 0;
    int cp = col < 127 ? col + 1 : 127;
    const float* fb = feat + (size_t)b * 128 * HW;

    float sc[9];
#pragma unroll
    for (int k = 0; k < 9; ++k) sc[k] = 0.f;
    float g = 0.f;

#pragma unroll
    for (int t = 0; t < 8; ++t) {
        float4 uu = *(const float4*)(u + t * 16 + q * 4);
#pragma unroll
        for (int r = 0; r < 4; ++r) {
            float zv = acc[t][r];
            const float* xc = fb + (size_t)(t * 16 + q * 4 + r) * HW;
            {   // dy = 0
                const float* xr = xc + a0;
                sc[0] += zv * xr[cm]; sc[1] += zv * xr[col]; sc[2] += zv * xr[cp];
            }
            {   // dy = 1 (center row; also feeds gamma)
                const float* xr = xc + a1;
                float x0 = xr[col];
                sc[3] += zv * xr[cm]; sc[4] += zv * x0; sc[5] += zv * xr[cp];
                g += ((const float*)&uu)[r] * x0;
            }
            {   // dy = 2
                const float* xr = xc + a2;
                sc[6] += zv * xr[cm]; sc[7] += zv * xr[col]; sc[8] += zv * xr[cp];
            }
        }
    }

    // ---- channel reduce across the 4 q-groups (lane bits 4,5)
#pragma unroll
    for (int k = 0; k < 9; ++k) {
        sc[k] += __shfl_xor(sc[k], 16);
        sc[k] += __shfl_xor(sc[k], 32);
    }
    g += __shfl_xor(g, 16);
    g += __shfl_xor(g, 32);

    // ---- softmax + flow gather (all lanes compute; q==0 lanes store)
    const float inv = 0.08838834764831845f;       // 1/sqrt(128)
    float base = g + *dptr;
    bool rok0 = row > 0, rok2 = row < 127;
    bool cok0 = col > 0, cok2 = col < 127;
    bool vmask[9] = { rok0 && cok0, rok0, rok0 && cok2,
                      cok0,         true, cok2,
                      rok2 && cok0, rok2, rok2 && cok2 };

    float s[9];
    float mx = -1e30f;
#pragma unroll
    for (int k = 0; k < 9; ++k) {
        float sv = vmask[k] ? (sc[k] + base) * inv : 0.f;
        s[k] = sv;
        mx = fmaxf(mx, sv);
    }
    float e[9], sum = 0.f;
#pragma unroll
    for (int k = 0; k < 9; ++k) { e[k] = __expf(s[k] - mx); sum += e[k]; }
    float rs = 1.f / sum;

    const float* f0 = flow + (size_t)(b * 2) * HW;
    const float* f1 = f0 + HW;
    int av[3] = {a0, a1, a2};
    int cv[3] = {cm, col, cp};
    float o0 = 0.f, o1 = 0.f;
#pragma unroll
    for (int dy = 0; dy < 3; ++dy)
#pragma unroll
        for (int dx = 0; dx < 3; ++dx) {
            int k = dy * 3 + dx;
            float pr = vmask[k] ? e[k] * rs : 0.f;
            int off = av[dy] + cv[dx];
            o0 += pr * f0[off];
            o1 += pr * f1[off];
        }
    if (q == 0) {
        out[(size_t)(b * 2) * HW + p0 + col] = o0;
        out[(size_t)(b * 2 + 1) * HW + p0 + col] = o1;
    }
}

extern "C" void kernel_launch(void* const* d_in, const int* in_sizes, int n_in,
                              void* d_out, int out_size, void* d_ws, size_t ws_size,
                              hipStream_t stream) {
    const float* feat = (const float*)d_in[0];
    const float* flow = (const float*)d_in[1];
    const float* qw = (const float*)d_in[2];
    const float* qb = (const float*)d_in[3];
    const float* kw = (const float*)d_in[4];
    const float* kb = (const float*)d_in[5];

    float* ws = (float*)d_ws;
    float* u = ws;                              // 128
    float* v = ws + 128;                        // 128
    float* dptr = ws + 256;                     // 1 (pad to 512)
    unsigned short* MhT = (unsigned short*)(ws + 512);    // 16384 bf16 = 8192 fl
    unsigned short* MlT = (unsigned short*)(ws + 8704);   // 16384 bf16 = 8192 fl
    float* out = (float*)d_out;

    prep_kernel<<<129, 256, 0, stream>>>(qw, qb, kw, kb, MhT, MlT, u, v, dptr);
    fused_kernel<<<512, 512, 0, stream>>>(feat, MhT, MlT, u, v, dptr, flow, out);
}